// Round 8
// baseline (2110.714 us; speedup 1.0000x reference)
//
#include <hip/hip_runtime.h>
#include <hip/hip_fp16.h>

typedef _Float16 half8 __attribute__((ext_vector_type(8)));
typedef float floatx4 __attribute__((ext_vector_type(4)));
typedef unsigned int uintx4 __attribute__((ext_vector_type(4)));

#define INPUT  512
#define HIDDEN 1024
#define OUTPUT 256
#define BATCH  128
#define SEQ    512

// ---------------------------------------------------------------------------
// K0: transpose + fp32->fp16:  W_h [K][N] f32 -> WhT [N][K] f16
// ---------------------------------------------------------------------------
__global__ __launch_bounds__(256) void transpose_f32_to_f16(
    const float* __restrict__ in, _Float16* __restrict__ out, int K, int N) {
  __shared__ float tile[32][33];
  int bi = blockIdx.x;
  int bj = blockIdx.y;
  int cc = threadIdx.x & 31;
  int rr = threadIdx.x >> 5;
#pragma unroll
  for (int s = 0; s < 4; ++s) {
    int r = rr + 8 * s;
    tile[r][cc] = in[(size_t)(bi * 32 + r) * N + bj * 32 + cc];
  }
  __syncthreads();
#pragma unroll
  for (int s = 0; s < 4; ++s) {
    int nl = rr + 8 * s;
    out[(size_t)(bj * 32 + nl) * K + bi * 32 + cc] = (_Float16)tile[cc][nl];
  }
}

// ---------------------------------------------------------------------------
// K0b: pack W_in [512][1024] f32 into MFMA B-fragment order (fp16).
// ---------------------------------------------------------------------------
__global__ __launch_bounds__(256) void pack_win(
    const float* __restrict__ W, _Float16* __restrict__ P) {
  int idx = blockIdx.x * 256 + threadIdx.x;   // 0..524287
  int k = idx >> 10, n = idx & 1023;
  P[((size_t)(k >> 5) << 15) + (n << 5) + (k & 31)] = (_Float16)W[idx];
}

// ---------------------------------------------------------------------------
// K1: xin[S][B][H] = x @ W_in  (time-major). 64x128 tile, 4 waves,
// 8 ntiles/wave, packed-fragment B loads.  (validated, R6/R7)
// ---------------------------------------------------------------------------
__global__ __launch_bounds__(256) void xin_gemm(
    const float* __restrict__ x, const _Float16* __restrict__ WinP,
    _Float16* __restrict__ xin) {
  int bid = blockIdx.x;                     // 8192 blocks
  int bm = (bid & 7) * 128 + ((bid >> 3) & 127);   // 0..1023
  int bn = bid >> 10;                       // 0..7
  int tid = threadIdx.x;
  int l = tid & 63;
  int w = tid >> 6;
  int l15 = l & 15;
  int lk = (l >> 4) << 3;

  int rowbase = bm * 64 + w * 16;
  int colbase = bn * 128;

  floatx4 acc[8];
#pragma unroll
  for (int nt = 0; nt < 8; ++nt) acc[nt] = (floatx4){0.f, 0.f, 0.f, 0.f};

  const float* xrow = x + (size_t)(rowbase + l15) * INPUT;

  for (int k0 = 0; k0 < INPUT; k0 += 32) {
    int ak = k0 + lk;
    float4 xa = *reinterpret_cast<const float4*>(xrow + ak);
    float4 xb = *reinterpret_cast<const float4*>(xrow + ak + 4);
    half8 a;
    a[0] = (_Float16)xa.x; a[1] = (_Float16)xa.y;
    a[2] = (_Float16)xa.z; a[3] = (_Float16)xa.w;
    a[4] = (_Float16)xb.x; a[5] = (_Float16)xb.y;
    a[6] = (_Float16)xb.z; a[7] = (_Float16)xb.w;
    const _Float16* pq = WinP + ((size_t)(k0 >> 5) << 15) + l15 * 32 + lk;
#pragma unroll
    for (int nt = 0; nt < 8; ++nt) {
      half8 b = *reinterpret_cast<const half8*>(pq + (colbase + nt * 16) * 32);
      acc[nt] = __builtin_amdgcn_mfma_f32_16x16x32_f16(a, b, acc[nt], 0, 0, 0);
    }
  }

  int orow = rowbase + ((l >> 4) << 2);
#pragma unroll
  for (int nt = 0; nt < 8; ++nt)
#pragma unroll
    for (int i = 0; i < 4; ++i) {
      int r = orow + i;
      int b = r >> 9;
      int s = r & 511;
      xin[((size_t)s * BATCH + b) * HIDDEN + colbase + nt * 16 + l15] =
          (_Float16)acc[nt][i];
    }
}

// ---------------------------------------------------------------------------
// K2: persistent recurrence — TRANSPOSED MFMA, zero-staging exchange.
// 128 blocks = 8 batch-groups (16 rows, -> XCD m) x 16 N-slices (64 cols).
// D[n][b] = sum_k WhT[n][k] * h[b][k]:  A = W (stationary VGPR), B = h.
// Wave w (0..7) owns K-slice [128w,128w+128): its 8 poll dwordx4 ARE its
// B-fragments (tagged); strip tags in-register with v_perm. No LDS staging,
// no pre-MFMA barrier — each wave proceeds when ITS 2 producers land.
// LDS only for the 8-way K-partial reduction (b128 writes / b64 reads).
// Finalize: thread tid owns (b = tid>>5, n-pair 2*(tid&31)) -> one u64
// tagged store (2 self-validating u32 words; tearing harmless).
// ---------------------------------------------------------------------------
__global__ __launch_bounds__(512) void liquid_scan(
    const _Float16* __restrict__ xin,   // [S][B][H]
    const _Float16* __restrict__ WhT,   // [H n][H k]
    const float* __restrict__ b_in, const float* __restrict__ b_h,
    const float* __restrict__ tau,
    unsigned int* hbuf,                 // [2][8][16][1024] tagged u32
    float* __restrict__ hfinal) {       // [B][H] f32
  int blk = blockIdx.x;
  int m = blk & 7;                  // batch group -> XCD m (perf heuristic)
  int j = blk >> 3;                 // N slice, 0..15
  int tid = threadIdx.x;
  int l = tid & 63;
  int w = tid >> 6;                 // 0..7 : K-slice owner
  int l15 = l & 15;                 // batch col b
  int hi = l >> 4;                  // k sub-chunk

  // [w][nt][lane*4+i], w-stride 1028 f32 (keeps w-reads on distinct banks)
  __shared__ float part_f[8 * 1028];

  // ---- stationary W A-fragments: wf[qq][nt], 64 VGPR ----
  half8 wf[4][4];
#pragma unroll
  for (int qq = 0; qq < 4; ++qq)
#pragma unroll
    for (int nt = 0; nt < 4; ++nt)
      wf[qq][nt] = *reinterpret_cast<const half8*>(
          WhT + (size_t)(j * 64 + nt * 16 + l15) * HIDDEN + w * 128 +
          qq * 32 + hi * 8);

  // ---- finalize mapping: thread -> (b, n-pair) ----
  const int bb = tid >> 5;               // 0..15
  const int n0 = (tid & 31) * 2;         // 0..62, even
  const int gn = j * 64 + n0;            // global col (within HIDDEN)
  const int gb = m * 16 + bb;            // global batch row
  const float bias0 = b_in[gn] + b_h[gn];
  const float bias1 = b_in[gn + 1] + b_h[gn + 1];
  const float it0 = 1.0f / tau[gn];
  const float it1 = 1.0f / tau[gn + 1];
  float h0 = 0.f, h1 = 0.f;
  const int nt_ = n0 >> 4;
  const int hi_ = (n0 >> 2) & 3;
  const int i_ = n0 & 3;                 // 0 or 2
  const int rbase = nt_ * 256 + (bb + (hi_ << 4)) * 4 + i_;

  // ---- poll base: lane reads row b=l15, k-cols 128w+8hi (+imm offsets) ----
  unsigned int* gpoll = hbuf + m * 16384 + l15 * 1024 + w * 128 + hi * 8;

  // ---- xin 2-deep u32 pipeline (pair gn, gn+1) ----
  const unsigned* xu = reinterpret_cast<const unsigned*>(xin);
  const size_t xoff = (size_t)gb * 512 + (gn >> 1);
  unsigned xc = xu[(size_t)0 * 65536 + xoff];
  unsigned x1v = xu[(size_t)1 * 65536 + xoff];

  for (int t = 0; t < SEQ; ++t) {
    floatx4 acc[4];
#pragma unroll
    for (int nt = 0; nt < 4; ++nt) acc[nt] = (floatx4){0.f, 0.f, 0.f, 0.f};

    if (t > 0) {
      unsigned int* bp = gpoll + (size_t)(t & 1) * 131072;
      const unsigned want = (unsigned)t;
      uintx4 q0, q1, q2, q3, q4, q5, q6, q7;
      for (;;) {
        // fused issue+wait (R5 lesson); one addr + immediate offsets
        asm volatile(
            "global_load_dwordx4 %0, %8, off sc1\n\t"
            "global_load_dwordx4 %1, %8, off offset:16 sc1\n\t"
            "global_load_dwordx4 %2, %8, off offset:128 sc1\n\t"
            "global_load_dwordx4 %3, %8, off offset:144 sc1\n\t"
            "global_load_dwordx4 %4, %8, off offset:256 sc1\n\t"
            "global_load_dwordx4 %5, %8, off offset:272 sc1\n\t"
            "global_load_dwordx4 %6, %8, off offset:384 sc1\n\t"
            "global_load_dwordx4 %7, %8, off offset:400 sc1\n\t"
            "s_waitcnt vmcnt(0)"
            : "=&v"(q0), "=&v"(q1), "=&v"(q2), "=&v"(q3),
              "=&v"(q4), "=&v"(q5), "=&v"(q6), "=&v"(q7)
            : "v"(bp)
            : "memory");
        unsigned bad = 0;
#define CH(Q) bad |= ((Q[0] ^ want) | (Q[1] ^ want) | (Q[2] ^ want) | \
                      (Q[3] ^ want)) & 0xFFFFu;
        CH(q0) CH(q1) CH(q2) CH(q3) CH(q4) CH(q5) CH(q6) CH(q7)
#undef CH
        if (!__any((int)(bad != 0u))) break;
      }
      // strip tags in-register -> B-fragments (h), then MFMA
      uintx4 u;
      half8 hf[4];
      u[0] = __builtin_amdgcn_perm(q0[1], q0[0], 0x07060302u);
      u[1] = __builtin_amdgcn_perm(q0[3], q0[2], 0x07060302u);
      u[2] = __builtin_amdgcn_perm(q1[1], q1[0], 0x07060302u);
      u[3] = __builtin_amdgcn_perm(q1[3], q1[2], 0x07060302u);
      hf[0] = __builtin_bit_cast(half8, u);
      u[0] = __builtin_amdgcn_perm(q2[1], q2[0], 0x07060302u);
      u[1] = __builtin_amdgcn_perm(q2[3], q2[2], 0x07060302u);
      u[2] = __builtin_amdgcn_perm(q3[1], q3[0], 0x07060302u);
      u[3] = __builtin_amdgcn_perm(q3[3], q3[2], 0x07060302u);
      hf[1] = __builtin_bit_cast(half8, u);
      u[0] = __builtin_amdgcn_perm(q4[1], q4[0], 0x07060302u);
      u[1] = __builtin_amdgcn_perm(q4[3], q4[2], 0x07060302u);
      u[2] = __builtin_amdgcn_perm(q5[1], q5[0], 0x07060302u);
      u[3] = __builtin_amdgcn_perm(q5[3], q5[2], 0x07060302u);
      hf[2] = __builtin_bit_cast(half8, u);
      u[0] = __builtin_amdgcn_perm(q6[1], q6[0], 0x07060302u);
      u[1] = __builtin_amdgcn_perm(q6[3], q6[2], 0x07060302u);
      u[2] = __builtin_amdgcn_perm(q7[1], q7[0], 0x07060302u);
      u[3] = __builtin_amdgcn_perm(q7[3], q7[2], 0x07060302u);
      hf[3] = __builtin_bit_cast(half8, u);
#pragma unroll
      for (int qq = 0; qq < 4; ++qq)
#pragma unroll
        for (int nt = 0; nt < 4; ++nt)
          acc[nt] = __builtin_amdgcn_mfma_f32_16x16x32_f16(wf[qq][nt], hf[qq],
                                                           acc[nt], 0, 0, 0);
    }

    // xin prefetch for t+2 (resolved a full step later at the rotate)
    const int ts = (t + 2 < SEQ) ? t + 2 : SEQ - 1;
    const unsigned xnv = xu[(size_t)ts * 65536 + xoff];

    // K-partial exchange through LDS
#pragma unroll
    for (int nt = 0; nt < 4; ++nt)
      *reinterpret_cast<floatx4*>(&part_f[w * 1028 + nt * 256 + l * 4]) =
          acc[nt];
    __syncthreads();  // B1: partials visible

    float s0 = 0.f, s1 = 0.f;
#pragma unroll
    for (int k = 0; k < 8; ++k) {
      const int w2 = (hi_ + k) & 7;   // rotation spreads banks across lanes
      const float2 p =
          *reinterpret_cast<const float2*>(&part_f[w2 * 1028 + rbase]);
      s0 += p.x; s1 += p.y;
    }
    __syncthreads();  // B2: reads done (WAR vs next step's writes)

    // finalize 2 outputs
    const float xv0 =
        (float)__builtin_bit_cast(_Float16, (unsigned short)(xc & 0xFFFFu));
    const float xv1 =
        (float)__builtin_bit_cast(_Float16, (unsigned short)(xc >> 16));
    float pre0 = s0 + xv0 + bias0;
    float pre1 = s1 + xv1 + bias1;
    pre0 = fminf(fmaxf(pre0, -15.f), 15.f);
    pre1 = fminf(fmaxf(pre1, -15.f), 15.f);
    const float e0 = __expf(2.f * pre0), e1 = __expf(2.f * pre1);
    const float dx0 = (e0 - 1.f) / (e0 + 1.f), dx1 = (e1 - 1.f) / (e1 + 1.f);
    h0 += (dx0 - h0) * it0;
    h1 += (dx1 - h1) * it1;

    if (t < SEQ - 1) {
      const unsigned short hb0 = __builtin_bit_cast(unsigned short, (_Float16)h0);
      const unsigned short hb1 = __builtin_bit_cast(unsigned short, (_Float16)h1);
      const unsigned w0 = ((unsigned)hb0 << 16) | (unsigned)(t + 1);
      const unsigned w1 = ((unsigned)hb1 << 16) | (unsigned)(t + 1);
      const unsigned long long dw = (unsigned long long)w0 |
                                    ((unsigned long long)w1 << 32);
      unsigned long long* p = reinterpret_cast<unsigned long long*>(
          hbuf + (size_t)((t + 1) & 1) * 131072 + m * 16384 + bb * 1024 + gn);
      __hip_atomic_store(p, dw, __ATOMIC_RELAXED, __HIP_MEMORY_SCOPE_AGENT);
    } else {
      *reinterpret_cast<float2*>(&hfinal[(size_t)gb * HIDDEN + gn]) =
          (float2){h0, h1};
    }
    xc = x1v;
    x1v = xnv;
  }
}

// ---------------------------------------------------------------------------
// K3: out[B][256] = hfinal @ W_out + b_out
// ---------------------------------------------------------------------------
__global__ __launch_bounds__(256) void out_gemm(
    const float* __restrict__ hfinal, const float* __restrict__ Wout,
    const float* __restrict__ bout, float* __restrict__ out) {
  int b0 = blockIdx.x * 2;
  int o = threadIdx.x;
  float a0 = 0.f, a1 = 0.f;
  for (int k = 0; k < HIDDEN; ++k) {
    float wv = Wout[(size_t)k * OUTPUT + o];
    a0 += hfinal[(size_t)b0 * HIDDEN + k] * wv;
    a1 += hfinal[(size_t)(b0 + 1) * HIDDEN + k] * wv;
  }
  out[(size_t)b0 * OUTPUT + o] = a0 + bout[o];
  out[(size_t)(b0 + 1) * OUTPUT + o] = a1 + bout[o];
}

// ---------------------------------------------------------------------------
extern "C" void kernel_launch(void* const* d_in, const int* in_sizes, int n_in,
                              void* d_out, int out_size, void* d_ws,
                              size_t ws_size, hipStream_t stream) {
  const float* x     = (const float*)d_in[0];
  const float* W_in  = (const float*)d_in[1];
  const float* b_in  = (const float*)d_in[2];
  const float* W_h   = (const float*)d_in[3];
  const float* b_h   = (const float*)d_in[4];
  const float* tau   = (const float*)d_in[5];
  const float* W_out = (const float*)d_in[6];
  const float* b_out = (const float*)d_in[7];
  float* out = (float*)d_out;

  char* ws = (char*)d_ws;
  _Float16* xin = (_Float16*)ws;  ws += (size_t)BATCH * SEQ * HIDDEN * 2;  // 134MB
  _Float16* WinP = (_Float16*)ws; ws += (size_t)INPUT * HIDDEN * 2;        // 1MB
  _Float16* WhT = (_Float16*)ws;  ws += (size_t)HIDDEN * HIDDEN * 2;       // 2MB
  unsigned int* hbuf = (unsigned int*)ws;
  ws += (size_t)2 * BATCH * HIDDEN * 4;                                    // 1MB
  float* hfin = (float*)ws;       ws += (size_t)BATCH * HIDDEN * 4;        // 512KB

  // zero tags (tag 0 never polled: t=0 skips poll/MFMA since h_0 = 0)
  hipMemsetAsync(hbuf, 0, (size_t)2 * BATCH * HIDDEN * 4, stream);

  transpose_f32_to_f16<<<dim3(HIDDEN / 32, HIDDEN / 32), 256, 0, stream>>>(
      W_h, WhT, HIDDEN, HIDDEN);
  pack_win<<<(INPUT * HIDDEN) / 256, 256, 0, stream>>>(W_in, WinP);

  xin_gemm<<<(BATCH * SEQ / 64) * (HIDDEN / 128), 256, 0, stream>>>(x, WinP,
                                                                    xin);

  liquid_scan<<<128, 512, 0, stream>>>(xin, WhT, b_in, b_h, tau, hbuf, hfin);

  out_gemm<<<BATCH / 2, OUTPUT, 0, stream>>>(hfin, W_out, b_out, out);
}